// Round 4
// baseline (452.206 us; speedup 1.0000x reference)
//
#include <hip/hip_runtime.h>
#include <cstdint>
#include <cstddef>

// GraphSAGE 2-layer fused pipeline, MI355X.
// Identity: segment_mean(x[src]) @ W == segment_mean((x@W)[src]) -> GEMM before gather.
// Inputs f32 (verified: bf16 reinterpret gave NaN, f32 gives finite). Output f32.
// Intermediates bf16-stored / f32-computed. Fixed-cap neighbor buckets (cap=64).

#define CAP 64

__device__ __forceinline__ float bf2f(unsigned short u) {
  return __uint_as_float(((unsigned int)u) << 16);
}
__device__ __forceinline__ unsigned short f2bf(float f) {
  unsigned int x = __float_as_uint(f);
  unsigned int r = (x + 0x7fffu + ((x >> 16) & 1u)) >> 16;  // RNE
  return (unsigned short)r;
}

// ---------------- neighbor buckets ----------------
__global__ void k_bucket(const int* __restrict__ ei, int* __restrict__ cnt,
                         int* __restrict__ bucket, int E) {
  int e = blockIdx.x * 256 + threadIdx.x;
  if (e >= E) return;
  int s = ei[e];        // src
  int d = ei[E + e];    // dst
  int p = atomicAdd(&cnt[d], 1);
  if (p < CAP) bucket[(size_t)d * CAP + p] = s;
}

// ---------------- layer-1 GEMMs: xl = x@W1l, hroot = x@W1r + b1 ----------------
__global__ __launch_bounds__(512) void k_gemm1(
    const float* __restrict__ x,
    const float* __restrict__ W1l,
    const float* __restrict__ W1r,
    const float* __restrict__ b1,
    unsigned short* __restrict__ xl,
    unsigned short* __restrict__ hroot,
    int Nn) {
  __shared__ float lwl[128 * 64];  // 32 KB
  __shared__ float lwr[128 * 64];  // 32 KB
  for (int i = threadIdx.x; i < 128 * 64; i += blockDim.x) {
    lwl[i] = W1l[i];
    lwr[i] = W1r[i];
  }
  __syncthreads();
  const int lane = threadIdx.x & 63;
  const int gw = blockIdx.x * (blockDim.x >> 6) + (threadIdx.x >> 6);
  const int nw = gridDim.x * (blockDim.x >> 6);
  const float bj = b1[lane];
  for (int base = gw * 4; base < Nn; base += nw * 4) {
    const int i1 = min(base + 1, Nn - 1);
    const int i2 = min(base + 2, Nn - 1);
    const int i3 = min(base + 3, Nn - 1);
    const float* x0p = x + (size_t)base * 128;
    const float* x1p = x + (size_t)i1 * 128;
    const float* x2p = x + (size_t)i2 * 128;
    const float* x3p = x + (size_t)i3 * 128;
    float a0 = 0.f, a1 = 0.f, a2 = 0.f, a3 = 0.f;
    float r0 = 0.f, r1 = 0.f, r2 = 0.f, r3 = 0.f;
    #pragma unroll 4
    for (int k = 0; k < 128; ++k) {
      const float wl = lwl[k * 64 + lane];
      const float wr = lwr[k * 64 + lane];
      const float xv0 = x0p[k];
      const float xv1 = x1p[k];
      const float xv2 = x2p[k];
      const float xv3 = x3p[k];
      a0 = fmaf(xv0, wl, a0); r0 = fmaf(xv0, wr, r0);
      a1 = fmaf(xv1, wl, a1); r1 = fmaf(xv1, wr, r1);
      a2 = fmaf(xv2, wl, a2); r2 = fmaf(xv2, wr, r2);
      a3 = fmaf(xv3, wl, a3); r3 = fmaf(xv3, wr, r3);
    }
    xl[(size_t)base * 64 + lane] = f2bf(a0);
    hroot[(size_t)base * 64 + lane] = f2bf(r0 + bj);
    if (base + 1 < Nn) { xl[(size_t)i1 * 64 + lane] = f2bf(a1); hroot[(size_t)i1 * 64 + lane] = f2bf(r1 + bj); }
    if (base + 2 < Nn) { xl[(size_t)i2 * 64 + lane] = f2bf(a2); hroot[(size_t)i2 * 64 + lane] = f2bf(r2 + bj); }
    if (base + 3 < Nn) { xl[(size_t)i3 * 64 + lane] = f2bf(a3); hroot[(size_t)i3 * 64 + lane] = f2bf(r3 + bj); }
  }
}

// ---------------- layer-1 aggregate: h = relu(mean_nb(xl) + hroot), wave per node ----------------
__global__ __launch_bounds__(256) void k_agg1(
    const int* __restrict__ cnt, const int* __restrict__ bucket,
    const unsigned short* __restrict__ xl, const unsigned short* __restrict__ hroot,
    unsigned short* __restrict__ hbuf, int Nn) {
  const int lane = threadIdx.x & 63;
  const int gw = blockIdx.x * (blockDim.x >> 6) + (threadIdx.x >> 6);
  const int nw = gridDim.x * (blockDim.x >> 6);
  for (int n = gw; n < Nn; n += nw) {
    int c = cnt[n];
    int m = c < CAP ? c : CAP;
    int sidx = (lane < m) ? bucket[(size_t)n * CAP + lane] : 0;
    if ((unsigned)sidx >= (unsigned)Nn) sidx = 0;  // firewall
    float acc = 0.f;
    int i = 0;
    for (; i + 4 <= m; i += 4) {
      int s0 = __shfl(sidx, i, 64);
      int s1 = __shfl(sidx, i + 1, 64);
      int s2 = __shfl(sidx, i + 2, 64);
      int s3 = __shfl(sidx, i + 3, 64);
      float v0 = bf2f(xl[(size_t)s0 * 64 + lane]);
      float v1 = bf2f(xl[(size_t)s1 * 64 + lane]);
      float v2 = bf2f(xl[(size_t)s2 * 64 + lane]);
      float v3 = bf2f(xl[(size_t)s3 * 64 + lane]);
      acc += (v0 + v1) + (v2 + v3);
    }
    for (; i < m; ++i) {
      int s = __shfl(sidx, i, 64);
      acc += bf2f(xl[(size_t)s * 64 + lane]);
    }
    float dd = c > 0 ? (float)c : 1.f;
    float hv = acc / dd + bf2f(hroot[(size_t)n * 64 + lane]);
    hbuf[(size_t)n * 64 + lane] = f2bf(fmaxf(hv, 0.f));
  }
}

// ---------------- layer-2 GEMMs: hl = h@W2l, hr = h@W2r + b2 ; thread per row ----------------
__global__ __launch_bounds__(128) void k_gemm2(
    const unsigned short* __restrict__ hbuf,
    const float* __restrict__ W2l, const float* __restrict__ W2r,
    const float* __restrict__ b2,
    float* __restrict__ hl, float* __restrict__ hr, int Nn) {
  __shared__ float tile[128 * 65];  // +1 pad: conflict-free column reads
  const int t = threadIdx.x;
  const int rowbase = blockIdx.x * 128;
  for (int idx = t; idx < 128 * 64; idx += 128) {
    int r = idx >> 6, k = idx & 63;
    int n = rowbase + r;
    tile[r * 65 + k] = (n < Nn) ? bf2f(hbuf[(size_t)n * 64 + k]) : 0.f;
  }
  __syncthreads();
  int n = rowbase + t;
  if (n >= Nn) return;
  float al[7] = {0, 0, 0, 0, 0, 0, 0};
  float ar[7] = {0, 0, 0, 0, 0, 0, 0};
  for (int k = 0; k < 64; ++k) {
    float hv = tile[t * 65 + k];
    #pragma unroll
    for (int c = 0; c < 7; ++c) {
      al[c] = fmaf(hv, W2l[k * 7 + c], al[c]);
      ar[c] = fmaf(hv, W2r[k * 7 + c], ar[c]);
    }
  }
  #pragma unroll
  for (int c = 0; c < 7; ++c) {
    hl[(size_t)n * 7 + c] = al[c];
    hr[(size_t)n * 7 + c] = ar[c] + b2[c];
  }
}

// ---------------- layer-2 aggregate + log_softmax; 8 nodes/wave, 8 lanes/node ----------------
__global__ __launch_bounds__(256) void k_out(
    const int* __restrict__ cnt, const int* __restrict__ bucket,
    const float* __restrict__ hl, const float* __restrict__ hr,
    float* __restrict__ out, int Nn) {
  const int lane = threadIdx.x & 63;
  const int c = lane & 7;
  const int sub = lane >> 3;
  const int gw = blockIdx.x * (blockDim.x >> 6) + (threadIdx.x >> 6);
  const int n = gw * 8 + sub;
  if (n >= Nn) return;
  int cn = cnt[n];
  int m = cn < CAP ? cn : CAP;
  const bool act = (c < 7);
  float acc = 0.f;
  for (int e = 0; e < m; ++e) {
    int s = bucket[(size_t)n * CAP + e];  // group-uniform
    if ((unsigned)s >= (unsigned)Nn) s = 0;
    if (act) acc += hl[(size_t)s * 7 + c];
  }
  float dd = cn > 0 ? (float)cn : 1.f;
  float v = act ? (acc / dd + hr[(size_t)n * 7 + c]) : -INFINITY;
  float mx = v;
  mx = fmaxf(mx, __shfl_xor(mx, 1, 8));
  mx = fmaxf(mx, __shfl_xor(mx, 2, 8));
  mx = fmaxf(mx, __shfl_xor(mx, 4, 8));
  float ex = act ? expf(v - mx) : 0.f;
  float s2 = ex;
  s2 += __shfl_xor(s2, 1, 8);
  s2 += __shfl_xor(s2, 2, 8);
  s2 += __shfl_xor(s2, 4, 8);
  float res = v - mx - logf(s2);
  if (act) out[(size_t)n * 7 + c] = res;
}

static inline size_t alignup(size_t v) { return (v + 255) & ~(size_t)255; }

extern "C" void kernel_launch(void* const* d_in, const int* in_sizes, int n_in,
                              void* d_out, int out_size, void* d_ws, size_t ws_size,
                              hipStream_t stream) {
  const int N = in_sizes[0] / 128;
  const int E = in_sizes[1] / 2;

  const float* x   = (const float*)d_in[0];
  const int*   ei  = (const int*)d_in[1];
  const float* W1l = (const float*)d_in[2];
  const float* W1r = (const float*)d_in[3];
  const float* b1  = (const float*)d_in[4];
  const float* W2l = (const float*)d_in[5];
  const float* W2r = (const float*)d_in[6];
  const float* b2  = (const float*)d_in[7];
  float* out = (float*)d_out;

  // workspace carve (~70 MB)
  char* p = (char*)d_ws;
  int* cnt    = (int*)p;             p += alignup((size_t)N * 4);
  int* bucket = (int*)p;             p += alignup((size_t)N * CAP * 4);
  unsigned short* xl    = (unsigned short*)p; p += alignup((size_t)N * 64 * 2);
  unsigned short* hroot = (unsigned short*)p; p += alignup((size_t)N * 64 * 2);
  unsigned short* hbuf  = (unsigned short*)p; p += alignup((size_t)N * 64 * 2);
  float* hl  = (float*)p;            p += alignup((size_t)N * 7 * 4);
  float* hr  = (float*)p;            p += alignup((size_t)N * 7 * 4);

  hipMemsetAsync(cnt, 0, (size_t)N * 4, stream);

  dim3 b256(256);
  k_bucket<<<dim3((E + 255) / 256), b256, 0, stream>>>(ei, cnt, bucket, E);
  k_gemm1<<<dim3(256), dim3(512), 0, stream>>>(x, W1l, W1r, b1, xl, hroot, N);
  k_agg1<<<dim3(2048), b256, 0, stream>>>(cnt, bucket, xl, hroot, hbuf, N);
  k_gemm2<<<dim3((N + 127) / 128), dim3(128), 0, stream>>>(hbuf, W2l, W2r, b2, hl, hr, N);
  const int waves_out = (N + 7) / 8;
  k_out<<<dim3((waves_out + 3) / 4), b256, 0, stream>>>(cnt, bucket, hl, hr, out, N);
}

// Round 5
// 419.462 us; speedup vs baseline: 1.0781x; 1.0781x over previous
//
#include <hip/hip_runtime.h>
#include <cstdint>
#include <cstddef>

// GraphSAGE 2-layer fused pipeline, MI355X.
// Identity: segment_mean(x[src]) @ W == segment_mean((x@W)[src]) -> GEMM before gather.
// Inputs f32, output f32. Intermediates bf16-stored / f32-computed. Bucket CSR (cap=64).
// R5: k_gemm1 rewritten: 8 rows/wave, float2-interleaved W in LDS (1 ds_read_b64/k),
//     scalar (wave-uniform) x loads w/ 1-step prefetch, exact single-pass grid.

#define CAP 64

__device__ __forceinline__ float bf2f(unsigned short u) {
  return __uint_as_float(((unsigned int)u) << 16);
}
__device__ __forceinline__ unsigned short f2bf(float f) {
  unsigned int x = __float_as_uint(f);
  unsigned int r = (x + 0x7fffu + ((x >> 16) & 1u)) >> 16;  // RNE
  return (unsigned short)r;
}

// ---------------- neighbor buckets ----------------
__global__ void k_bucket(const int* __restrict__ ei, int* __restrict__ cnt,
                         int* __restrict__ bucket, int E) {
  int e = blockIdx.x * 256 + threadIdx.x;
  if (e >= E) return;
  int s = ei[e];        // src
  int d = ei[E + e];    // dst
  int p = atomicAdd(&cnt[d], 1);
  if (p < CAP) bucket[(size_t)d * CAP + p] = s;
}

// ---------------- layer-1 GEMMs: xl = x@W1l, hroot = x@W1r + b1 ----------------
// 64 rows/block (8 waves x 8 rows). lane = output column.
__global__ __launch_bounds__(512) void k_gemm1(
    const float* __restrict__ x,
    const float* __restrict__ W1l,
    const float* __restrict__ W1r,
    const float* __restrict__ b1,
    unsigned short* __restrict__ xl,
    unsigned short* __restrict__ hroot,
    int Nn) {
  __shared__ float2 w[128 * 64];  // 64 KB: {W1l, W1r} interleaved, k-major
  for (int i = threadIdx.x; i < 128 * 64; i += 512) {
    w[i] = make_float2(W1l[i], W1r[i]);
  }
  __syncthreads();
  const int lane = threadIdx.x & 63;
  const int wid = threadIdx.x >> 6;
  int rowbase = blockIdx.x * 64 + wid * 8;
  rowbase = __builtin_amdgcn_readfirstlane(rowbase);  // force SGPR -> scalar x loads
  if (rowbase >= Nn) return;
  const float bj = b1[lane];

  const float* xr[8];
  #pragma unroll
  for (int r = 0; r < 8; ++r) {
    int rr = rowbase + r;
    if (rr > Nn - 1) rr = Nn - 1;
    xr[r] = x + (size_t)rr * 128;
  }

  float al[8], ar[8];
  #pragma unroll
  for (int r = 0; r < 8; ++r) { al[r] = 0.f; ar[r] = 0.f; }

  // prefetch k0=0
  float4 nxt[8];
  #pragma unroll
  for (int r = 0; r < 8; ++r) nxt[r] = *(const float4*)(xr[r]);

  for (int k0 = 0; k0 < 128; k0 += 4) {
    float cur[8][4];
    #pragma unroll
    for (int r = 0; r < 8; ++r) {
      cur[r][0] = nxt[r].x; cur[r][1] = nxt[r].y;
      cur[r][2] = nxt[r].z; cur[r][3] = nxt[r].w;
    }
    if (k0 + 4 < 128) {
      #pragma unroll
      for (int r = 0; r < 8; ++r) nxt[r] = *(const float4*)(xr[r] + k0 + 4);
    }
    #pragma unroll
    for (int kk = 0; kk < 4; ++kk) {
      const float2 wv = w[(k0 + kk) * 64 + lane];
      #pragma unroll
      for (int r = 0; r < 8; ++r) {
        al[r] = fmaf(cur[r][kk], wv.x, al[r]);
        ar[r] = fmaf(cur[r][kk], wv.y, ar[r]);
      }
    }
  }

  #pragma unroll
  for (int r = 0; r < 8; ++r) {
    int rr = rowbase + r;
    if (rr < Nn) {
      xl[(size_t)rr * 64 + lane] = f2bf(al[r]);
      hroot[(size_t)rr * 64 + lane] = f2bf(ar[r] + bj);
    }
  }
}

// ---------------- layer-1 aggregate: h = relu(mean_nb(xl) + hroot), wave per node ----------------
__global__ __launch_bounds__(256) void k_agg1(
    const int* __restrict__ cnt, const int* __restrict__ bucket,
    const unsigned short* __restrict__ xl, const unsigned short* __restrict__ hroot,
    unsigned short* __restrict__ hbuf, int Nn) {
  const int lane = threadIdx.x & 63;
  const int gw = blockIdx.x * (blockDim.x >> 6) + (threadIdx.x >> 6);
  const int nw = gridDim.x * (blockDim.x >> 6);
  for (int n = gw; n < Nn; n += nw) {
    int c = cnt[n];
    int m = c < CAP ? c : CAP;
    int sidx = (lane < m) ? bucket[(size_t)n * CAP + lane] : 0;
    if ((unsigned)sidx >= (unsigned)Nn) sidx = 0;  // firewall
    float acc = 0.f;
    int i = 0;
    for (; i + 4 <= m; i += 4) {
      int s0 = __shfl(sidx, i, 64);
      int s1 = __shfl(sidx, i + 1, 64);
      int s2 = __shfl(sidx, i + 2, 64);
      int s3 = __shfl(sidx, i + 3, 64);
      float v0 = bf2f(xl[(size_t)s0 * 64 + lane]);
      float v1 = bf2f(xl[(size_t)s1 * 64 + lane]);
      float v2 = bf2f(xl[(size_t)s2 * 64 + lane]);
      float v3 = bf2f(xl[(size_t)s3 * 64 + lane]);
      acc += (v0 + v1) + (v2 + v3);
    }
    for (; i < m; ++i) {
      int s = __shfl(sidx, i, 64);
      acc += bf2f(xl[(size_t)s * 64 + lane]);
    }
    float dd = c > 0 ? (float)c : 1.f;
    float hv = acc / dd + bf2f(hroot[(size_t)n * 64 + lane]);
    hbuf[(size_t)n * 64 + lane] = f2bf(fmaxf(hv, 0.f));
  }
}

// ---------------- layer-2 GEMMs: hl = h@W2l, hr = h@W2r + b2 ; thread per row ----------------
__global__ __launch_bounds__(128) void k_gemm2(
    const unsigned short* __restrict__ hbuf,
    const float* __restrict__ W2l, const float* __restrict__ W2r,
    const float* __restrict__ b2,
    float* __restrict__ hl, float* __restrict__ hr, int Nn) {
  __shared__ float tile[128 * 65];  // +1 pad: conflict-free column reads
  const int t = threadIdx.x;
  const int rowbase = blockIdx.x * 128;
  for (int idx = t; idx < 128 * 64; idx += 128) {
    int r = idx >> 6, k = idx & 63;
    int n = rowbase + r;
    tile[r * 65 + k] = (n < Nn) ? bf2f(hbuf[(size_t)n * 64 + k]) : 0.f;
  }
  __syncthreads();
  int n = rowbase + t;
  if (n >= Nn) return;
  float al[7] = {0, 0, 0, 0, 0, 0, 0};
  float ar[7] = {0, 0, 0, 0, 0, 0, 0};
  for (int k = 0; k < 64; ++k) {
    float hv = tile[t * 65 + k];
    #pragma unroll
    for (int c = 0; c < 7; ++c) {
      al[c] = fmaf(hv, W2l[k * 7 + c], al[c]);
      ar[c] = fmaf(hv, W2r[k * 7 + c], ar[c]);
    }
  }
  #pragma unroll
  for (int c = 0; c < 7; ++c) {
    hl[(size_t)n * 7 + c] = al[c];
    hr[(size_t)n * 7 + c] = ar[c] + b2[c];
  }
}

// ---------------- layer-2 aggregate + log_softmax; 8 nodes/wave, 8 lanes/node ----------------
__global__ __launch_bounds__(256) void k_out(
    const int* __restrict__ cnt, const int* __restrict__ bucket,
    const float* __restrict__ hl, const float* __restrict__ hr,
    float* __restrict__ out, int Nn) {
  const int lane = threadIdx.x & 63;
  const int c = lane & 7;
  const int sub = lane >> 3;
  const int gw = blockIdx.x * (blockDim.x >> 6) + (threadIdx.x >> 6);
  const int n = gw * 8 + sub;
  if (n >= Nn) return;
  int cn = cnt[n];
  int m = cn < CAP ? cn : CAP;
  const bool act = (c < 7);
  float acc = 0.f;
  for (int e = 0; e < m; ++e) {
    int s = bucket[(size_t)n * CAP + e];  // group-uniform
    if ((unsigned)s >= (unsigned)Nn) s = 0;
    if (act) acc += hl[(size_t)s * 7 + c];
  }
  float dd = cn > 0 ? (float)cn : 1.f;
  float v = act ? (acc / dd + hr[(size_t)n * 7 + c]) : -INFINITY;
  float mx = v;
  mx = fmaxf(mx, __shfl_xor(mx, 1, 8));
  mx = fmaxf(mx, __shfl_xor(mx, 2, 8));
  mx = fmaxf(mx, __shfl_xor(mx, 4, 8));
  float ex = act ? expf(v - mx) : 0.f;
  float s2 = ex;
  s2 += __shfl_xor(s2, 1, 8);
  s2 += __shfl_xor(s2, 2, 8);
  s2 += __shfl_xor(s2, 4, 8);
  float res = v - mx - logf(s2);
  if (act) out[(size_t)n * 7 + c] = res;
}

static inline size_t alignup(size_t v) { return (v + 255) & ~(size_t)255; }

extern "C" void kernel_launch(void* const* d_in, const int* in_sizes, int n_in,
                              void* d_out, int out_size, void* d_ws, size_t ws_size,
                              hipStream_t stream) {
  const int N = in_sizes[0] / 128;
  const int E = in_sizes[1] / 2;

  const float* x   = (const float*)d_in[0];
  const int*   ei  = (const int*)d_in[1];
  const float* W1l = (const float*)d_in[2];
  const float* W1r = (const float*)d_in[3];
  const float* b1  = (const float*)d_in[4];
  const float* W2l = (const float*)d_in[5];
  const float* W2r = (const float*)d_in[6];
  const float* b2  = (const float*)d_in[7];
  float* out = (float*)d_out;

  // workspace carve (~70 MB)
  char* p = (char*)d_ws;
  int* cnt    = (int*)p;             p += alignup((size_t)N * 4);
  int* bucket = (int*)p;             p += alignup((size_t)N * CAP * 4);
  unsigned short* xl    = (unsigned short*)p; p += alignup((size_t)N * 64 * 2);
  unsigned short* hroot = (unsigned short*)p; p += alignup((size_t)N * 64 * 2);
  unsigned short* hbuf  = (unsigned short*)p; p += alignup((size_t)N * 64 * 2);
  float* hl  = (float*)p;            p += alignup((size_t)N * 7 * 4);
  float* hr  = (float*)p;            p += alignup((size_t)N * 7 * 4);

  hipMemsetAsync(cnt, 0, (size_t)N * 4, stream);

  dim3 b256(256);
  k_bucket<<<dim3((E + 255) / 256), b256, 0, stream>>>(ei, cnt, bucket, E);
  k_gemm1<<<dim3((N + 63) / 64), dim3(512), 0, stream>>>(x, W1l, W1r, b1, xl, hroot, N);
  k_agg1<<<dim3(2048), b256, 0, stream>>>(cnt, bucket, xl, hroot, hbuf, N);
  k_gemm2<<<dim3((N + 127) / 128), dim3(128), 0, stream>>>(hbuf, W2l, W2r, b2, hl, hr, N);
  const int waves_out = (N + 7) / 8;
  k_out<<<dim3((waves_out + 3) / 4), b256, 0, stream>>>(cnt, bucket, hl, hr, out, N);
}